// Round 6
// baseline (13735.245 us; speedup 1.0000x reference)
//
#include <hip/hip_runtime.h>

#define NSEQ 2048
#define BATCH 16
#define HDIM 256
#define PDIM 256
#define NLAYER 4

typedef unsigned short u16;

__device__ __forceinline__ float gelu_tanh(float x) {
    float z = 0.7978845608028654f * (x + 0.044715f * x * x * x);
    return 0.5f * x * (1.f + tanhf(z));
}

// ---------------- LayerNorm fp32, dead-simple LDS tree ----------------
__global__ void ln_f32(const float* u, const float* sc, const float* bs, float* out) {
    __shared__ float red[256];
    __shared__ float stat[2];
    const int t = blockIdx.x, h = threadIdx.x;
    const float x = u[(size_t)t * 256 + h];
    red[h] = x;
    __syncthreads();
    for (int s = 128; s > 0; s >>= 1) {
        if (h < s) red[h] += red[h + s];
        __syncthreads();
    }
    if (h == 0) stat[0] = red[0] * (1.f / 256.f);
    __syncthreads();
    const float d = x - stat[0];
    red[h] = d * d;
    __syncthreads();
    for (int s = 128; s > 0; s >>= 1) {
        if (h < s) red[h] += red[h + s];
        __syncthreads();
    }
    if (h == 0) stat[1] = rsqrtf(red[0] * (1.f / 256.f) + 1e-5f);
    __syncthreads();
    out[(size_t)t * 256 + h] = d * stat[1] * sc[h] + bs[h];
}

// ---------------- fp32 GEMM, weights in NATIVE (K,256) layout ----------------
constexpr int EPI_DUP = 0, EPI_PLAIN = 1;

template <int EPI>
__global__ void sgemm256(const float* A, const float* W, const float* bias,
                         float* o1, float* o2, int ldo, int colofs) {
    __shared__ float As[256];
    const int m = blockIdx.x, n = threadIdx.x;
    As[n] = A[(size_t)m * 256 + n];
    __syncthreads();
    float a0 = 0.f, a1 = 0.f, a2 = 0.f, a3 = 0.f;
    for (int k = 0; k < 256; k += 4) {
        a0 += As[k]     * W[(size_t)k * 256 + n];
        a1 += As[k + 1] * W[(size_t)(k + 1) * 256 + n];
        a2 += As[k + 2] * W[(size_t)(k + 2) * 256 + n];
        a3 += As[k + 3] * W[(size_t)(k + 3) * 256 + n];
    }
    float acc = (a0 + a1) + (a2 + a3);
    if (bias) acc += bias[n];
    if constexpr (EPI == EPI_DUP) {
        o1[(size_t)m * 256 + n] = acc;
        o2[(size_t)m * 256 + n] = acc;
    } else {
        o1[(size_t)m * ldo + colofs + n] = acc;
    }
}

// g[m][n] = gelu( sum_k re[m][k]*C_re[k][n] - im[m][k]*C_im[k][n] ), A=(M,512)=[re|im]
__global__ void sgemmC(const float* A, const float* Cre, const float* Cim, float* g) {
    __shared__ float As[512];
    const int m = blockIdx.x, n = threadIdx.x;
    As[n]       = A[(size_t)m * 512 + n];
    As[n + 256] = A[(size_t)m * 512 + 256 + n];
    __syncthreads();
    float a0 = 0.f, a1 = 0.f;
    for (int k = 0; k < 256; k += 2) {
        a0 += As[k]     * Cre[(size_t)k * 256 + n]       - As[256 + k]     * Cim[(size_t)k * 256 + n];
        a1 += As[k + 1] * Cre[(size_t)(k + 1) * 256 + n] - As[256 + k + 1] * Cim[(size_t)(k + 1) * 256 + n];
    }
    g[(size_t)m * 256 + n] = gelu_tanh(a0 + a1);
}

// ---------------- sequential complex scan, one block per sequence ----------------
// Xr may alias Bu: per-thread read-before-write at the same address.
__global__ void scan_seq(const float* Bu, const float* dt, const float* Lre,
                         const float* Lim, const float* ldl, const float* ire,
                         const float* iim, float* Xr, float* Xl) {
    const int b = blockIdx.x, p = threadIdx.x;
    const float lam_r = -expf(Lre[p]);
    const float lam_i = Lim[p];
    const float del = expf(ldl[p]);
    float xr = ire[p], xi = iim[p];
    for (int n = 0; n < NSEQ; ++n) {
        const float e = dt[b * NSEQ + n] * del;
        const float amag = expf(lam_r * e);
        float sn, cs;
        sincosf(lam_i * e, &sn, &cs);
        const float are = amag * cs, aim = amag * sn;
        const size_t tok = ((size_t)b * NSEQ + n) * 512;
        const float bre = Bu[tok + p];
        const float bim = Bu[tok + 256 + p];
        const float lr = are * xr - aim * xi;   // x_left = a * x_prev
        const float li = are * xi + aim * xr;
        const float rr = lr + bre;              // x_right = x_left + Bu
        const float ri = li + bim;
        Xl[tok + p] = lr;
        Xl[tok + 256 + p] = li;
        Xr[tok + p] = rr;
        Xr[tok + 256 + p] = ri;
        xr = rr; xi = ri;
    }
}

// ---------------- GLU combine + residual add ----------------
__global__ void glu_add(float* u, const float* t) {
    const int token = blockIdx.x, h = threadIdx.x;
    const size_t base = (size_t)token * 512;
    const float t1 = t[base + h];
    const float t2 = t[base + 256 + h];
    u[(size_t)token * 256 + h] += t1 * (1.f / (1.f + expf(-t2)));
}

// ---------------- zero token 0 of each sequence ----------------
__global__ void zero_first(float* out) {
    out[(size_t)blockIdx.x * NSEQ * HDIM + threadIdx.x] = 0.f;
}

extern "C" void kernel_launch(void* const* d_in, const int* in_sizes, int n_in,
                              void* d_out, int out_size, void* d_ws, size_t ws_size,
                              hipStream_t stream) {
    const float* x_payload = (const float*)d_in[0];
    const float* dt        = (const float*)d_in[1];
    const float* embed_W   = (const float*)d_in[2];
    const float* embed_b   = (const float*)d_in[3];
    const float* ln_scale  = (const float*)d_in[4];
    const float* ln_bias   = (const float*)d_in[5];
    const float* Lambda_re = (const float*)d_in[6];
    const float* Lambda_im = (const float*)d_in[7];
    const float* log_delta = (const float*)d_in[8];
    const float* B_re      = (const float*)d_in[9];
    const float* B_im      = (const float*)d_in[10];
    const float* C_re      = (const float*)d_in[11];
    const float* C_im      = (const float*)d_in[12];
    const float* W1        = (const float*)d_in[13];
    const float* b1        = (const float*)d_in[14];
    const float* W2        = (const float*)d_in[15];
    const float* b2        = (const float*)d_in[16];
    const float* init_re   = (const float*)d_in[17];
    const float* init_im   = (const float*)d_in[18];

    auto footprint = [](int g) -> size_t {
        size_t T = (size_t)g * NSEQ;
        return T * 256 * 4 + T * 256 * 4 + T * 512 * 4 + T * 512 * 4 + 4096;
    };
    int g = BATCH;
    while (g > 1 && footprint(g) > ws_size) g >>= 1;

    char* ws = (char*)d_ws;
    size_t off = 0;
    auto alloc = [&](size_t bytes) {
        void* p = ws + off;
        off = (off + bytes + 255) & ~(size_t)255;
        return p;
    };
    const size_t T = (size_t)g * NSEQ;
    const int Tg = (int)T;
    float* u_r  = (float*)alloc(T * 256 * 4);
    float* vbuf = (float*)alloc(T * 256 * 4);   // v_r; reused as gelu buffer
    float* BuB  = (float*)alloc(T * 512 * 4);   // Bu -> Xr (in place) -> tbuf
    float* Xl   = (float*)alloc(T * 512 * 4);
    float* Xr   = BuB;
    float* tbuf = BuB;
    float* gbuf = vbuf;

    for (int b0 = 0; b0 < BATCH; b0 += g) {
        const float* xg  = x_payload + (size_t)b0 * NSEQ * HDIM;
        const float* dtg = dt + (size_t)b0 * NSEQ;
        float* u_l = (float*)d_out + (size_t)b0 * NSEQ * HDIM;  // left stream in d_out

        sgemm256<EPI_DUP><<<Tg, 256, 0, stream>>>(xg, embed_W, embed_b, u_r, u_l, 0, 0);

        for (int l = 0; l < NLAYER; ++l) {
            const float* Brl = B_re + (size_t)l * 65536;
            const float* Bil = B_im + (size_t)l * 65536;
            const float* Crl = C_re + (size_t)l * 65536;
            const float* Cil = C_im + (size_t)l * 65536;
            const float* W1l = W1 + (size_t)l * 65536;
            const float* W2l = W2 + (size_t)l * 65536;
            const float* b1l = b1 + (size_t)l * 256;
            const float* b2l = b2 + (size_t)l * 256;
            // v_r = LN(right_u)   (v_l is dead code in the reference)
            ln_f32<<<Tg, 256, 0, stream>>>(u_r, ln_scale + l * HDIM, ln_bias + l * HDIM, vbuf);
            // Bu = [v_r @ B_re | v_r @ B_im]
            sgemm256<EPI_PLAIN><<<Tg, 256, 0, stream>>>(vbuf, Brl, nullptr, BuB, nullptr, 512, 0);
            sgemm256<EPI_PLAIN><<<Tg, 256, 0, stream>>>(vbuf, Bil, nullptr, BuB, nullptr, 512, 256);
            // sequential scan -> Xr (in place over Bu), Xl
            scan_seq<<<g, 256, 0, stream>>>(BuB, dtg, Lambda_re + l * PDIM,
                                            Lambda_im + l * PDIM, log_delta + l * PDIM,
                                            init_re + l * PDIM, init_im + l * PDIM, Xr, Xl);
            if (l < NLAYER - 1) {   // right-stream update unused after last layer
                sgemmC<<<Tg, 256, 0, stream>>>(Xr, Crl, Cil, gbuf);
                sgemm256<EPI_PLAIN><<<Tg, 256, 0, stream>>>(gbuf, W1l, b1l, tbuf, nullptr, 512, 0);
                sgemm256<EPI_PLAIN><<<Tg, 256, 0, stream>>>(gbuf, W2l, b2l, tbuf, nullptr, 512, 256);
                glu_add<<<Tg, 256, 0, stream>>>(u_r, tbuf);
            }
            sgemmC<<<Tg, 256, 0, stream>>>(Xl, Crl, Cil, gbuf);
            sgemm256<EPI_PLAIN><<<Tg, 256, 0, stream>>>(gbuf, W1l, b1l, tbuf, nullptr, 512, 0);
            sgemm256<EPI_PLAIN><<<Tg, 256, 0, stream>>>(gbuf, W2l, b2l, tbuf, nullptr, 512, 256);
            glu_add<<<Tg, 256, 0, stream>>>(u_l, tbuf);
        }
        zero_first<<<g, 256, 0, stream>>>(u_l);
    }
}